// Round 7
// baseline (548.885 us; speedup 1.0000x reference)
//
#include <hip/hip_runtime.h>
#include <cstdint>
#include <cstddef>

// ---------------- problem constants ----------------
#define DD 1024          // feature dim (= K = N per GEMM)
#define TT 8192          // sequence length
#define BB 4             // batch
#define MM (BB*TT)       // 32768 rows
#define NCHUNK 64        // scan chunks over T
#define CLEN 128         // chunk length (NCHUNK*CLEN == TT)
#define EPS 1e-5f
#define NK2 16           // K tiles of 64 (DD/64)

typedef __attribute__((ext_vector_type(8))) short bf16x8;
typedef __attribute__((ext_vector_type(4))) float f32x4;

// ---------------- bf16 helpers (bit-level, RNE) ----------------
__device__ __forceinline__ float bf2f(unsigned short b) {
  union { unsigned int u; float f; } c; c.u = ((unsigned int)b) << 16; return c.f;
}
__device__ __forceinline__ unsigned short f2bf(float f) {
  union { float f; unsigned int u; } c; c.f = f;
  unsigned int lsb = (c.u >> 16) & 1u;
  c.u += 0x7fffu + lsb;
  return (unsigned short)(c.u >> 16);
}

// ---------------- async global->LDS (16B per lane) ----------------
__device__ __forceinline__ void gload16(const void* gsrc, void* ldst) {
  __builtin_amdgcn_global_load_lds(
      (const __attribute__((address_space(1))) unsigned int*)gsrc,
      (__attribute__((address_space(3))) unsigned int*)ldst, 16, 0, 0);
}

// LDS slot swizzle over [R][32]-packed k-half tiles: row = 64B = 4 slots of
// 16B; phys_slot = log_slot ^ ((row>>1)&3). Verified 0 bank conflicts (R3-R6).
#define SWZ(row) (((row) >> 1) & 3)

// Read one MFMA B fragment (16 rows x 8 k) from a swizzled k-half tile.
__device__ __forceinline__ bf16x8 ldsfrag(const unsigned short* lds, int row, int sl) {
  int sp = sl ^ SWZ(row);
  return *(const bf16x8*)&lds[row * 32 + sp * 8];
}

#define MFMA16(a, b, c) __builtin_amdgcn_mfma_f32_16x16x32_bf16((a), (b), (c), 0, 0, 0)

#define VMCNT0 asm volatile("s_waitcnt vmcnt(0)" ::: "memory")
#define BAR    __builtin_amdgcn_s_barrier()

// ---------------- kernel 1: cast weights to bf16 ----------------
__global__ __launch_bounds__(256) void cast_weights(
    const float* __restrict__ wg, const float* __restrict__ wv,
    const float* __restrict__ wo,
    unsigned short* __restrict__ owg, unsigned short* __restrict__ owv,
    unsigned short* __restrict__ owo) {
  int i = blockIdx.x * 256 + threadIdx.x;   // over float4 units; 3*262144 total
  const float* src; unsigned short* dst; int off;
  if (i < 262144)       { src = wg; dst = owg; off = i; }
  else if (i < 524288)  { src = wv; dst = owv; off = i - 262144; }
  else                  { src = wo; dst = owo; off = i - 524288; }
  float4 v = ((const float4*)src)[off];
  ushort4 o;
  o.x = f2bf(v.x); o.y = f2bf(v.y); o.z = f2bf(v.z); o.w = f2bf(v.w);
  ((ushort4*)dst)[off] = o;
}

// ---------------- kernel 2: LayerNorm -> bf16 ----------------
__global__ __launch_bounds__(256) void ln_kernel(
    const float* __restrict__ x, const float* __restrict__ gamma,
    const float* __restrict__ beta, unsigned short* __restrict__ normed) {
  size_t row = blockIdx.x;
  int tid = threadIdx.x, lane = tid & 63, wid = tid >> 6;
  float4 v = ((const float4*)(x + row * DD))[tid];
  float s = v.x + v.y + v.z + v.w;
  float q = v.x * v.x + v.y * v.y + v.z * v.z + v.w * v.w;
#pragma unroll
  for (int off = 32; off; off >>= 1) {
    s += __shfl_down(s, off);
    q += __shfl_down(q, off);
  }
  __shared__ float rs[4], rq[4];
  if (lane == 0) { rs[wid] = s; rq[wid] = q; }
  __syncthreads();
  float ts = rs[0] + rs[1] + rs[2] + rs[3];
  float tq = rq[0] + rq[1] + rq[2] + rq[3];
  float mu  = ts * (1.0f / DD);
  float var = tq * (1.0f / DD) - mu * mu;
  float rstd = rsqrtf(var + EPS);
  float4 gm = ((const float4*)gamma)[tid];
  float4 bt = ((const float4*)beta)[tid];
  ushort4 o;
  o.x = f2bf((v.x - mu) * rstd * gm.x + bt.x);
  o.y = f2bf((v.y - mu) * rstd * gm.y + bt.y);
  o.z = f2bf((v.z - mu) * rstd * gm.z + bt.z);
  o.w = f2bf((v.w - mu) * rstd * gm.w + bt.w);
  ((ushort4*)normed)[row * (DD / 4) + tid] = o;
}

// ---------------- kernel 3: fused gate/value GEMM -> u (+ chunk sums) ------
// 256x128 tile, BK=64, 8 waves (2M x 4N), wave owns 128x32 of BOTH outputs.
// A-fragments load DIRECTLY global->VGPR (L2-resident via XCD swizzle);
// only B (Wg,Wv) is LDS-staged. One raw barrier + vmcnt(0) per K-tile.
__global__ __launch_bounds__(512, 2) void gemm_gv(
    const unsigned short* __restrict__ normed,
    const unsigned short* __restrict__ wg, const unsigned short* __restrict__ wv,
    const float* __restrict__ bg, const float* __restrict__ bv,
    unsigned short* __restrict__ u, float* __restrict__ sums) {
  __shared__ unsigned short Bgs[2][2][128 * 32];  // [buf][khalf] 16 KiB
  __shared__ unsigned short Bvs[2][2][128 * 32];  // 16 KiB  (total 64 KiB)
  int tid = threadIdx.x, lane = tid & 63, wid = tid >> 6;
  int wm = wid >> 2, wn = wid & 3;         // 2 M-groups x 4 N-groups
  int nwg = gridDim.x;                     // 1024, %8==0
  int swz = (blockIdx.x & 7) * (nwg >> 3) + (blockIdx.x >> 3);
  int bx = swz >> 3;                       // M block (128); by fastest ->
  int by = swz & 7;                        // XCD owns contiguous bx chunk
  size_t m0 = (size_t)bx * 256;
  int n0 = by * 128;

  // B staging invariants (512 thr, 1 gload16 per 128x32 k-half)
  int rowq = tid >> 2, sp = tid & 3;
  int sl0 = sp ^ SWZ(rowq);
  const unsigned short* eBg = wg + ((size_t)n0 + rowq) * DD + sl0 * 8;
  const unsigned short* eBv = wv + ((size_t)n0 + rowq) * DD + sl0 * 8;
  auto SB = [&](int t1) {   // stage both k-halves of tile t1 (4 ops, oldest)
    int k0 = t1 * 64;
    gload16(eBg + k0,      (char*)&Bgs[t1 & 1][0][0] + tid * 16);
    gload16(eBv + k0,      (char*)&Bvs[t1 & 1][0][0] + tid * 16);
    gload16(eBg + k0 + 32, (char*)&Bgs[t1 & 1][1][0] + tid * 16);
    gload16(eBv + k0 + 32, (char*)&Bvs[t1 & 1][1][0] + tid * 16);
  };

  int r = lane & 15, q = lane >> 4;
  // A direct-load base: lane covers row (wm*128 + mi*16 + r), bytes q*16
  const unsigned short* aBase = normed + (m0 + wm * 128 + r) * DD + q * 8;

  f32x4 accg[8][2], accv[8][2];
#pragma unroll
  for (int a = 0; a < 8; ++a)
#pragma unroll
    for (int b = 0; b < 2; ++b) {
      accg[a][b] = (f32x4){0.f, 0.f, 0.f, 0.f};
      accv[a][b] = (f32x4){0.f, 0.f, 0.f, 0.f};
    }

  bf16x8 af0[8], af1[8];
  SB(0);
#pragma unroll
  for (int mi = 0; mi < 8; ++mi)
    af0[mi] = *(const bf16x8*)(aBase + (size_t)mi * 16 * DD);
  VMCNT0;
  BAR;

  for (int t = 0; t < NK2; ++t) {
    int buf = t & 1;
    bool more = (t + 1 < NK2);
    bf16x8 g0, g1, v0, v1;
    // stage B of next tile first (keeps them oldest in vm queue)
    if (more) SB(t + 1);
    // kh0 B frags
    g0 = ldsfrag(Bgs[buf][0], wn * 32 + r, q);
    g1 = ldsfrag(Bgs[buf][0], wn * 32 + 16 + r, q);
    v0 = ldsfrag(Bvs[buf][0], wn * 32 + r, q);
    v1 = ldsfrag(Bvs[buf][0], wn * 32 + 16 + r, q);
    // issue A kh1 loads
#pragma unroll
    for (int mi = 0; mi < 8; ++mi)
      af1[mi] = *(const bf16x8*)(aBase + (size_t)mi * 16 * DD + t * 64 + 32);
    // kh0 MFMA (af0)
    __builtin_amdgcn_s_setprio(1);
#pragma unroll
    for (int mi = 0; mi < 8; ++mi) {
      accg[mi][0] = MFMA16(af0[mi], g0, accg[mi][0]);
      accg[mi][1] = MFMA16(af0[mi], g1, accg[mi][1]);
      accv[mi][0] = MFMA16(af0[mi], v0, accv[mi][0]);
      accv[mi][1] = MFMA16(af0[mi], v1, accv[mi][1]);
    }
    __builtin_amdgcn_s_setprio(0);
    // kh1 B frags
    g0 = ldsfrag(Bgs[buf][1], wn * 32 + r, q);
    g1 = ldsfrag(Bgs[buf][1], wn * 32 + 16 + r, q);
    v0 = ldsfrag(Bvs[buf][1], wn * 32 + r, q);
    v1 = ldsfrag(Bvs[buf][1], wn * 32 + 16 + r, q);
    // issue A kh0 loads of next tile (af0 WAR resolved: consumed above)
    if (more) {
#pragma unroll
      for (int mi = 0; mi < 8; ++mi)
        af0[mi] = *(const bf16x8*)(aBase + (size_t)mi * 16 * DD + (t + 1) * 64);
    }
    // kh1 MFMA (af1)
    __builtin_amdgcn_s_setprio(1);
#pragma unroll
    for (int mi = 0; mi < 8; ++mi) {
      accg[mi][0] = MFMA16(af1[mi], g0, accg[mi][0]);
      accg[mi][1] = MFMA16(af1[mi], g1, accg[mi][1]);
      accv[mi][0] = MFMA16(af1[mi], v0, accv[mi][0]);
      accv[mi][1] = MFMA16(af1[mi], v1, accv[mi][1]);
    }
    __builtin_amdgcn_s_setprio(0);
    if (more) { VMCNT0; BAR; }   // B(t+1) landed; everything L2-aged -> cheap
  }

  // epilogue: u = (2*sigmoid(g)-1)*v, plus fused per-chunk partial sums.
  // C/D layout col=lane&15, row=(lane>>4)*4+j  [m89/m91 verified]
  float psum[2] = {0.f, 0.f};
#pragma unroll
  for (int mi = 0; mi < 8; ++mi)
#pragma unroll
    for (int ni = 0; ni < 2; ++ni) {
      int e = n0 + wn * 32 + ni * 16 + r;
      size_t rbase = m0 + wm * 128 + mi * 16 + q * 4;
      float bgv = bg[e], bvv = bv[e];
#pragma unroll
      for (int j = 0; j < 4; ++j) {
        float gp = accg[mi][ni][j] + bgv;
        float vp = accv[mi][ni][j] + bvv;
        float sg = 1.0f / (1.0f + __expf(-gp));
        float uu = (2.0f * sg - 1.0f) * vp;
        psum[ni] += uu;
        u[(rbase + j) * DD + e] = f2bf(uu);
      }
    }
#pragma unroll
  for (int ni = 0; ni < 2; ++ni) {
    psum[ni] += __shfl_xor(psum[ni], 16);
    psum[ni] += __shfl_xor(psum[ni], 32);
  }
  if (lane < 16) {
    int b = (int)(m0 >> 13);
    int ch = (int)((m0 & 8191) >> 7) + wm;
    size_t sidx = ((size_t)(b * NCHUNK + ch)) * DD + n0 + wn * 32 + lane;
    sums[sidx]      = psum[0];
    sums[sidx + 16] = psum[1];
  }
}

// ---------------- kernel 5: exclusive scan over chunk sums (in place) ------
__global__ __launch_bounds__(256) void scan_chunks(float* __restrict__ sums) {
  int b = blockIdx.x >> 2;
  int e = (blockIdx.x & 3) * 256 + threadIdx.x;
  float vals[NCHUNK];
#pragma unroll
  for (int c = 0; c < NCHUNK; ++c)
    vals[c] = sums[((size_t)(b * NCHUNK + c)) * DD + e];
  float carry = 0.f;
#pragma unroll
  for (int c = 0; c < NCHUNK; ++c) {
    float t = vals[c]; vals[c] = carry; carry += t;
  }
#pragma unroll
  for (int c = 0; c < NCHUNK; ++c)
    sums[((size_t)(b * NCHUNK + c)) * DD + e] = vals[c];
}

// ---------------- kernel 6: chunk-local scan + decay, in place ----------------
__global__ __launch_bounds__(128) void scan_final(
    unsigned short* __restrict__ u, const float* __restrict__ sums,
    const float* __restrict__ log_decay) {
  int bid = blockIdx.x;
  int half = bid & 1, chunk = (bid >> 1) & 63, b = bid >> 7;
  int e0 = half * 512 + threadIdx.x * 4;
  float alpha = log1pf(__expf(log_decay[0]));   // softplus
  float4 c = *(const float4*)(sums + ((size_t)(b * NCHUNK + chunk)) * DD + e0);
  size_t base = ((size_t)b * TT + (size_t)chunk * CLEN) * DD + e0;
#pragma unroll 4
  for (int i = 0; i < CLEN; ++i) {
    int t = chunk * CLEN + i;
    float dec = __expf(-alpha * (float)t);
    ushort4 w = *(const ushort4*)(u + base + (size_t)i * DD);
    c.x += bf2f(w.x); c.y += bf2f(w.y); c.z += bf2f(w.z); c.w += bf2f(w.w);
    ushort4 o;
    o.x = f2bf(c.x * dec); o.y = f2bf(c.y * dec);
    o.z = f2bf(c.z * dec); o.w = f2bf(c.w * dec);
    *(ushort4*)(u + base + (size_t)i * DD) = o;
  }
}

// ---------------- kernel 7: output GEMM + residual ----------------
// 256x256 tile, BK=64, 8 waves (2M x 4N), wave owns 128x64.
// Same A-direct/B-LDS single-barrier structure as gemm_gv.
// out[m,e] = x[m,e] + bo[e] + sum_d c[m,d]*Wo[e,d]
__global__ __launch_bounds__(512, 2) void gemm_out(
    const unsigned short* __restrict__ cmat, const unsigned short* __restrict__ wo,
    const float* __restrict__ bo, const float* __restrict__ x,
    float* __restrict__ out) {
  __shared__ unsigned short Bs[2][2][256 * 32];   // 64 KiB
  int tid = threadIdx.x, lane = tid & 63, wid = tid >> 6;
  int wm = wid >> 2, wn = wid & 3;         // 2 M-groups x 4 N-groups
  int nwg = gridDim.x;                     // 512, %8==0
  int swz = (blockIdx.x & 7) * (nwg >> 3) + (blockIdx.x >> 3);
  int bx = swz >> 2;                       // M block (128); by fastest
  int by = swz & 3;                        // N block (4)
  size_t m0 = (size_t)bx * 256;
  int n0 = by * 256;

  int rowq = tid >> 2, sp = tid & 3;
  int sl0 = sp ^ SWZ(rowq);
  const unsigned short* eB0 = wo + ((size_t)n0 + rowq) * DD + sl0 * 8;
  const unsigned short* eB1 = wo + ((size_t)n0 + 128 + rowq) * DD + sl0 * 8;
  auto SB = [&](int t1) {   // stage both k-halves of tile t1 (4 ops)
    int k0 = t1 * 64;
    char* d0 = (char*)&Bs[t1 & 1][0][0] + tid * 16;
    char* d1 = (char*)&Bs[t1 & 1][1][0] + tid * 16;
    gload16(eB0 + k0,      d0);
    gload16(eB1 + k0,      d0 + 8192);
    gload16(eB0 + k0 + 32, d1);
    gload16(eB1 + k0 + 32, d1 + 8192);
  };

  int r = lane & 15, q = lane >> 4;
  const unsigned short* aBase = cmat + (m0 + wm * 128 + r) * DD + q * 8;

  f32x4 acc[8][4];
#pragma unroll
  for (int a = 0; a < 8; ++a)
#pragma unroll
    for (int b = 0; b < 4; ++b) acc[a][b] = (f32x4){0.f, 0.f, 0.f, 0.f};

  bf16x8 af0[8], af1[8];
  SB(0);
#pragma unroll
  for (int mi = 0; mi < 8; ++mi)
    af0[mi] = *(const bf16x8*)(aBase + (size_t)mi * 16 * DD);
  VMCNT0;
  BAR;

  for (int t = 0; t < NK2; ++t) {
    int buf = t & 1;
    bool more = (t + 1 < NK2);
    bf16x8 b0, b1, b2, b3;
    if (more) SB(t + 1);
    // kh0 B frags
    b0 = ldsfrag(Bs[buf][0], wn * 64 + r, q);
    b1 = ldsfrag(Bs[buf][0], wn * 64 + 16 + r, q);
    b2 = ldsfrag(Bs[buf][0], wn * 64 + 32 + r, q);
    b3 = ldsfrag(Bs[buf][0], wn * 64 + 48 + r, q);
#pragma unroll
    for (int mi = 0; mi < 8; ++mi)
      af1[mi] = *(const bf16x8*)(aBase + (size_t)mi * 16 * DD + t * 64 + 32);
    __builtin_amdgcn_s_setprio(1);
#pragma unroll
    for (int mi = 0; mi < 8; ++mi) {
      acc[mi][0] = MFMA16(af0[mi], b0, acc[mi][0]);
      acc[mi][1] = MFMA16(af0[mi], b1, acc[mi][1]);
      acc[mi][2] = MFMA16(af0[mi], b2, acc[mi][2]);
      acc[mi][3] = MFMA16(af0[mi], b3, acc[mi][3]);
    }
    __builtin_amdgcn_s_setprio(0);
    // kh1 B frags
    b0 = ldsfrag(Bs[buf][1], wn * 64 + r, q);
    b1 = ldsfrag(Bs[buf][1], wn * 64 + 16 + r, q);
    b2 = ldsfrag(Bs[buf][1], wn * 64 + 32 + r, q);
    b3 = ldsfrag(Bs[buf][1], wn * 64 + 48 + r, q);
    if (more) {
#pragma unroll
      for (int mi = 0; mi < 8; ++mi)
        af0[mi] = *(const bf16x8*)(aBase + (size_t)mi * 16 * DD + (t + 1) * 64);
    }
    __builtin_amdgcn_s_setprio(1);
#pragma unroll
    for (int mi = 0; mi < 8; ++mi) {
      acc[mi][0] = MFMA16(af1[mi], b0, acc[mi][0]);
      acc[mi][1] = MFMA16(af1[mi], b1, acc[mi][1]);
      acc[mi][2] = MFMA16(af1[mi], b2, acc[mi][2]);
      acc[mi][3] = MFMA16(af1[mi], b3, acc[mi][3]);
    }
    __builtin_amdgcn_s_setprio(0);
    if (more) { VMCNT0; BAR; }
  }

#pragma unroll
  for (int mi = 0; mi < 8; ++mi)
#pragma unroll
    for (int nq = 0; nq < 4; ++nq) {
      int e = n0 + wn * 64 + nq * 16 + r;
      size_t rbase = m0 + wm * 128 + mi * 16 + q * 4;
      float bov = bo[e];
#pragma unroll
      for (int j = 0; j < 4; ++j) {
        size_t idx = (rbase + j) * DD + e;
        out[idx] = x[idx] + bov + acc[mi][nq][j];
      }
    }
}

// ---------------- launch ----------------
extern "C" void kernel_launch(void* const* d_in, const int* in_sizes, int n_in,
                              void* d_out, int out_size, void* d_ws, size_t ws_size,
                              hipStream_t stream) {
  const float* x     = (const float*)d_in[0];
  const float* gamma = (const float*)d_in[1];
  const float* beta  = (const float*)d_in[2];
  const float* Wg    = (const float*)d_in[3];
  const float* bg    = (const float*)d_in[4];
  const float* Wv    = (const float*)d_in[5];
  const float* bv    = (const float*)d_in[6];
  const float* Wo    = (const float*)d_in[7];
  const float* bo    = (const float*)d_in[8];
  const float* ldcy  = (const float*)d_in[9];
  float* out = (float*)d_out;

  char* ws = (char*)d_ws;
  // layout: normed bf16 (64MiB) | u/c bf16 (64MiB) | Wg,Wv,Wo bf16 (3x2MiB) | sums f32 (1MiB)
  unsigned short* normed = (unsigned short*)ws;
  unsigned short* u      = (unsigned short*)(ws + (size_t)67108864);
  unsigned short* wgb    = (unsigned short*)(ws + (size_t)134217728);
  unsigned short* wvb    = wgb + 1048576;
  unsigned short* wob    = wvb + 1048576;
  float* sums            = (float*)(ws + (size_t)134217728 + (size_t)3 * 2097152);

  cast_weights<<<3072, 256, 0, stream>>>(Wg, Wv, Wo, wgb, wvb, wob);
  ln_kernel<<<MM, 256, 0, stream>>>(x, gamma, beta, normed);
  gemm_gv<<<dim3(MM / 256 * (DD / 128)), 512, 0, stream>>>(normed, wgb, wvb, bg, bv, u, sums);
  scan_chunks<<<BB * (DD / 256), 256, 0, stream>>>(sums);
  scan_final<<<BB * NCHUNK * 2, 128, 0, stream>>>(u, sums, ldcy);
  gemm_out<<<dim3(MM / 256 * (DD / 256)), 512, 0, stream>>>(u, wob, bo, x, out);
}

// Round 8
// 355.336 us; speedup vs baseline: 1.5447x; 1.5447x over previous
//
#include <hip/hip_runtime.h>
#include <cstdint>
#include <cstddef>

// ---------------- problem constants ----------------
#define DD 1024          // feature dim (= K = N per GEMM)
#define TT 8192          // sequence length
#define BB 4             // batch
#define MM (BB*TT)       // 32768 rows
#define NCHUNK 64        // scan chunks over T
#define CLEN 128         // chunk length (NCHUNK*CLEN == TT)
#define EPS 1e-5f
#define NKT 32           // K tiles of 32 (DD/32)

typedef __attribute__((ext_vector_type(8))) short bf16x8;
typedef __attribute__((ext_vector_type(4))) float f32x4;

// ---------------- bf16 helpers (bit-level, RNE) ----------------
__device__ __forceinline__ float bf2f(unsigned short b) {
  union { unsigned int u; float f; } c; c.u = ((unsigned int)b) << 16; return c.f;
}
__device__ __forceinline__ unsigned short f2bf(float f) {
  union { float f; unsigned int u; } c; c.f = f;
  unsigned int lsb = (c.u >> 16) & 1u;
  c.u += 0x7fffu + lsb;
  return (unsigned short)(c.u >> 16);
}

// ---------------- async global->LDS (16B per lane) ----------------
__device__ __forceinline__ void gload16(const void* gsrc, void* ldst) {
  __builtin_amdgcn_global_load_lds(
      (const __attribute__((address_space(1))) unsigned int*)gsrc,
      (__attribute__((address_space(3))) unsigned int*)ldst, 16, 0, 0);
}

// LDS slot swizzle over [R][32]-packed tiles: row = 64B = 4 slots of 16B;
// phys_slot = log_slot ^ ((row>>1)&3). Verified 0 bank conflicts (R3-R6).
#define SWZ(row) (((row) >> 1) & 3)

// Read one MFMA A/B fragment (16 rows x 8 k) from a swizzled tile.
__device__ __forceinline__ bf16x8 ldsfrag(const unsigned short* lds, int row, int sl) {
  int sp = sl ^ SWZ(row);
  return *(const bf16x8*)&lds[row * 32 + sp * 8];
}

#define MFMA16(a, b, c) __builtin_amdgcn_mfma_f32_16x16x32_bf16((a), (b), (c), 0, 0, 0)

#define VMCNT0 asm volatile("s_waitcnt vmcnt(0)" ::: "memory")
#define BAR    __builtin_amdgcn_s_barrier()

// ---------------- kernel 1: cast weights to bf16 ----------------
__global__ __launch_bounds__(256) void cast_weights(
    const float* __restrict__ wg, const float* __restrict__ wv,
    const float* __restrict__ wo,
    unsigned short* __restrict__ owg, unsigned short* __restrict__ owv,
    unsigned short* __restrict__ owo) {
  int i = blockIdx.x * 256 + threadIdx.x;   // over float4 units; 3*262144 total
  const float* src; unsigned short* dst; int off;
  if (i < 262144)       { src = wg; dst = owg; off = i; }
  else if (i < 524288)  { src = wv; dst = owv; off = i - 262144; }
  else                  { src = wo; dst = owo; off = i - 524288; }
  float4 v = ((const float4*)src)[off];
  ushort4 o;
  o.x = f2bf(v.x); o.y = f2bf(v.y); o.z = f2bf(v.z); o.w = f2bf(v.w);
  ((ushort4*)dst)[off] = o;
}

// ---------------- kernel 2: LayerNorm -> bf16 ----------------
__global__ __launch_bounds__(256) void ln_kernel(
    const float* __restrict__ x, const float* __restrict__ gamma,
    const float* __restrict__ beta, unsigned short* __restrict__ normed) {
  size_t row = blockIdx.x;
  int tid = threadIdx.x, lane = tid & 63, wid = tid >> 6;
  float4 v = ((const float4*)(x + row * DD))[tid];
  float s = v.x + v.y + v.z + v.w;
  float q = v.x * v.x + v.y * v.y + v.z * v.z + v.w * v.w;
#pragma unroll
  for (int off = 32; off; off >>= 1) {
    s += __shfl_down(s, off);
    q += __shfl_down(q, off);
  }
  __shared__ float rs[4], rq[4];
  if (lane == 0) { rs[wid] = s; rq[wid] = q; }
  __syncthreads();
  float ts = rs[0] + rs[1] + rs[2] + rs[3];
  float tq = rq[0] + rq[1] + rq[2] + rq[3];
  float mu  = ts * (1.0f / DD);
  float var = tq * (1.0f / DD) - mu * mu;
  float rstd = rsqrtf(var + EPS);
  float4 gm = ((const float4*)gamma)[tid];
  float4 bt = ((const float4*)beta)[tid];
  ushort4 o;
  o.x = f2bf((v.x - mu) * rstd * gm.x + bt.x);
  o.y = f2bf((v.y - mu) * rstd * gm.y + bt.y);
  o.z = f2bf((v.z - mu) * rstd * gm.z + bt.z);
  o.w = f2bf((v.w - mu) * rstd * gm.w + bt.w);
  ((ushort4*)normed)[row * (DD / 4) + tid] = o;
}

// ---------------- kernel 3: fused gate/value GEMM -> u (+ chunk sums) ------
// 256x128 tile, BK=32, 16 waves (4M x 4N, 1024 thr), wave owns 64x32 of BOTH
// outputs -> acc = 64 VGPR. Single-barrier dbuf loop; 4 waves/SIMD hide
// latency. LDS 64 KB -> 2 blocks/CU if regs allow.
__global__ __launch_bounds__(1024, 4) void gemm_gv(
    const unsigned short* __restrict__ normed,
    const unsigned short* __restrict__ wg, const unsigned short* __restrict__ wv,
    const float* __restrict__ bg, const float* __restrict__ bv,
    unsigned short* __restrict__ u, float* __restrict__ sums) {
  __shared__ unsigned short As[2][256 * 32];   // 32 KiB
  __shared__ unsigned short Bgs[2][128 * 32];  // 16 KiB
  __shared__ unsigned short Bvs[2][128 * 32];  // 16 KiB
  int tid = threadIdx.x, lane = tid & 63, wid = tid >> 6;   // wid 0..15
  int wm = wid >> 2, wn = wid & 3;         // 4 M-groups x 4 N-groups
  int nwg = gridDim.x;                     // 1024, %8==0
  int swz = (blockIdx.x & 7) * (nwg >> 3) + (blockIdx.x >> 3);
  int bx = swz >> 3;                       // M block (128); by fastest ->
  int by = swz & 7;                        // XCD owns contiguous bx chunk
  size_t m0 = (size_t)bx * 256;
  int n0 = by * 128;

  // staging invariants: A tile 256x32 = 1 load/thread; B: low 512 thr -> Bg,
  // high 512 -> Bv (128x32 each = 1 load/thread)
  int rowA = tid >> 2, spA = tid & 3;
  int slA = spA ^ SWZ(rowA);
  const unsigned short* eA = normed + (m0 + rowA) * DD + slA * 8;
  int lowhalf = (tid < 512);
  int rtid = lowhalf ? tid : tid - 512;
  int rowB = rtid >> 2, spB = rtid & 3;
  int slB = spB ^ SWZ(rowB);
  const unsigned short* eB =
      (lowhalf ? wg : wv) + ((size_t)n0 + rowB) * DD + slB * 8;

  f32x4 accg[4][2], accv[4][2];
#pragma unroll
  for (int a = 0; a < 4; ++a)
#pragma unroll
    for (int b = 0; b < 2; ++b) {
      accg[a][b] = (f32x4){0.f, 0.f, 0.f, 0.f};
      accv[a][b] = (f32x4){0.f, 0.f, 0.f, 0.f};
    }

  // prologue: stage tile 0 (2 loads/thread)
  gload16(eA, (char*)&As[0][0] + tid * 16);
  gload16(eB, (lowhalf ? (char*)&Bgs[0][0] : (char*)&Bvs[0][0]) + rtid * 16);
  VMCNT0;
  BAR;

  int r = lane & 15, q = lane >> 4;
  for (int t = 0; t < NKT; ++t) {
    int buf = t & 1;
    bool more = (t + 1 < NKT);
    if (more) {   // stage tile t+1 into buf^1 (2 loads/thread)
      gload16(eA + (t + 1) * 32, (char*)&As[buf ^ 1][0] + tid * 16);
      gload16(eB + (t + 1) * 32,
              (lowhalf ? (char*)&Bgs[buf ^ 1][0] : (char*)&Bvs[buf ^ 1][0]) + rtid * 16);
    }
    bf16x8 af[4];
#pragma unroll
    for (int mi = 0; mi < 4; ++mi)
      af[mi] = ldsfrag(As[buf], wm * 64 + mi * 16 + r, q);
    bf16x8 g0 = ldsfrag(Bgs[buf], wn * 32 + r, q);
    bf16x8 g1 = ldsfrag(Bgs[buf], wn * 32 + 16 + r, q);
    bf16x8 v0 = ldsfrag(Bvs[buf], wn * 32 + r, q);
    bf16x8 v1 = ldsfrag(Bvs[buf], wn * 32 + 16 + r, q);
    __builtin_amdgcn_s_setprio(1);
#pragma unroll
    for (int mi = 0; mi < 4; ++mi) {
      accg[mi][0] = MFMA16(af[mi], g0, accg[mi][0]);
      accg[mi][1] = MFMA16(af[mi], g1, accg[mi][1]);
      accv[mi][0] = MFMA16(af[mi], v0, accv[mi][0]);
      accv[mi][1] = MFMA16(af[mi], v1, accv[mi][1]);
    }
    __builtin_amdgcn_s_setprio(0);
    if (more) { VMCNT0; BAR; }   // tile t+1 landed; all waves done with buf t
  }

  // epilogue: u = (2*sigmoid(g)-1)*v, fused per-chunk partial sums.
  // C/D layout col=lane&15, row=(lane>>4)*4+j  [m89/m91 verified]
  float psum[2] = {0.f, 0.f};
#pragma unroll
  for (int mi = 0; mi < 4; ++mi)
#pragma unroll
    for (int ni = 0; ni < 2; ++ni) {
      int e = n0 + wn * 32 + ni * 16 + r;
      size_t rbase = m0 + wm * 64 + mi * 16 + q * 4;
      float bgv = bg[e], bvv = bv[e];
#pragma unroll
      for (int j = 0; j < 4; ++j) {
        float gp = accg[mi][ni][j] + bgv;
        float vp = accv[mi][ni][j] + bvv;
        float sg = 1.0f / (1.0f + __expf(-gp));
        float uu = (2.0f * sg - 1.0f) * vp;
        psum[ni] += uu;
        u[(rbase + j) * DD + e] = f2bf(uu);
      }
    }
  // reduce psum over the 4 q-subgroups within the wave
#pragma unroll
  for (int ni = 0; ni < 2; ++ni) {
    psum[ni] += __shfl_xor(psum[ni], 16);
    psum[ni] += __shfl_xor(psum[ni], 32);
  }
  // cross-wave: wave covers 64 rows; chunk = 128 rows = wm pair {0,1},{2,3}
  float* S = (float*)&As[0][0];   // scratch [4][128] f32 (LDS reuse)
  BAR;                            // all waves done reading As
  if (lane < 16) {
    S[wm * 128 + wn * 32 + lane]      = psum[0];
    S[wm * 128 + wn * 32 + 16 + lane] = psum[1];
  }
  BAR;
  if (tid < 256) {
    int chh = tid >> 7, col = tid & 127;
    float vsum = S[(chh * 2) * 128 + col] + S[(chh * 2 + 1) * 128 + col];
    int b = (int)(m0 >> 13);
    int ch = (int)((m0 & 8191) >> 7) + chh;
    sums[((size_t)(b * NCHUNK + ch)) * DD + n0 + col] = vsum;
  }
}

// ---------------- kernel 5: exclusive scan over chunk sums (in place) ------
__global__ __launch_bounds__(256) void scan_chunks(float* __restrict__ sums) {
  int b = blockIdx.x >> 2;
  int e = (blockIdx.x & 3) * 256 + threadIdx.x;
  float vals[NCHUNK];
#pragma unroll
  for (int c = 0; c < NCHUNK; ++c)
    vals[c] = sums[((size_t)(b * NCHUNK + c)) * DD + e];
  float carry = 0.f;
#pragma unroll
  for (int c = 0; c < NCHUNK; ++c) {
    float t = vals[c]; vals[c] = carry; carry += t;
  }
#pragma unroll
  for (int c = 0; c < NCHUNK; ++c)
    sums[((size_t)(b * NCHUNK + c)) * DD + e] = vals[c];
}

// ---------------- kernel 6: chunk-local scan + decay, in place ----------------
__global__ __launch_bounds__(128) void scan_final(
    unsigned short* __restrict__ u, const float* __restrict__ sums,
    const float* __restrict__ log_decay) {
  int bid = blockIdx.x;
  int half = bid & 1, chunk = (bid >> 1) & 63, b = bid >> 7;
  int e0 = half * 512 + threadIdx.x * 4;
  float alpha = log1pf(__expf(log_decay[0]));   // softplus
  // incremental decay: dec(t+1) = dec(t)*step  (128 muls, drift ~1e-5 rel)
  float dec  = __expf(-alpha * (float)(chunk * CLEN));
  float step = __expf(-alpha);
  float4 c = *(const float4*)(sums + ((size_t)(b * NCHUNK + chunk)) * DD + e0);
  size_t base = ((size_t)b * TT + (size_t)chunk * CLEN) * DD + e0;
#pragma unroll 4
  for (int i = 0; i < CLEN; ++i) {
    ushort4 w = *(const ushort4*)(u + base + (size_t)i * DD);
    c.x += bf2f(w.x); c.y += bf2f(w.y); c.z += bf2f(w.z); c.w += bf2f(w.w);
    ushort4 o;
    o.x = f2bf(c.x * dec); o.y = f2bf(c.y * dec);
    o.z = f2bf(c.z * dec); o.w = f2bf(c.w * dec);
    *(ushort4*)(u + base + (size_t)i * DD) = o;
    dec *= step;
  }
}

// ---------------- kernel 7: output GEMM + residual ----------------
// 256x256 tile, BK=32, 16 waves (4M x 4N, 1024 thr), wave owns 64x64.
// Same single-barrier dbuf loop. out = x + bo + c@Wo^T
__global__ __launch_bounds__(1024, 4) void gemm_out(
    const unsigned short* __restrict__ cmat, const unsigned short* __restrict__ wo,
    const float* __restrict__ bo, const float* __restrict__ x,
    float* __restrict__ out) {
  __shared__ unsigned short As[2][256 * 32];   // 32 KiB
  __shared__ unsigned short Bs[2][256 * 32];   // 32 KiB
  int tid = threadIdx.x, lane = tid & 63, wid = tid >> 6;
  int wm = wid >> 2, wn = wid & 3;         // 4 M-groups x 4 N-groups
  int nwg = gridDim.x;                     // 512, %8==0
  int swz = (blockIdx.x & 7) * (nwg >> 3) + (blockIdx.x >> 3);
  int bx = swz >> 2;                       // M block (128); by fastest
  int by = swz & 3;                        // N block (4)
  size_t m0 = (size_t)bx * 256;
  int n0 = by * 256;

  int rowA = tid >> 2, spA = tid & 3;
  int slA = spA ^ SWZ(rowA);
  const unsigned short* eA = cmat + (m0 + rowA) * DD + slA * 8;
  const unsigned short* eB = wo + ((size_t)n0 + rowA) * DD + slA * 8;

  f32x4 acc[4][4];
#pragma unroll
  for (int a = 0; a < 4; ++a)
#pragma unroll
    for (int b = 0; b < 4; ++b) acc[a][b] = (f32x4){0.f, 0.f, 0.f, 0.f};

  gload16(eA, (char*)&As[0][0] + tid * 16);
  gload16(eB, (char*)&Bs[0][0] + tid * 16);
  VMCNT0;
  BAR;

  int r = lane & 15, q = lane >> 4;
  for (int t = 0; t < NKT; ++t) {
    int buf = t & 1;
    bool more = (t + 1 < NKT);
    if (more) {
      gload16(eA + (t + 1) * 32, (char*)&As[buf ^ 1][0] + tid * 16);
      gload16(eB + (t + 1) * 32, (char*)&Bs[buf ^ 1][0] + tid * 16);
    }
    bf16x8 af[4];
#pragma unroll
    for (int mi = 0; mi < 4; ++mi)
      af[mi] = ldsfrag(As[buf], wm * 64 + mi * 16 + r, q);
    bf16x8 b0 = ldsfrag(Bs[buf], wn * 64 + r, q);
    bf16x8 b1 = ldsfrag(Bs[buf], wn * 64 + 16 + r, q);
    bf16x8 b2 = ldsfrag(Bs[buf], wn * 64 + 32 + r, q);
    bf16x8 b3 = ldsfrag(Bs[buf], wn * 64 + 48 + r, q);
    __builtin_amdgcn_s_setprio(1);
#pragma unroll
    for (int mi = 0; mi < 4; ++mi) {
      acc[mi][0] = MFMA16(af[mi], b0, acc[mi][0]);
      acc[mi][1] = MFMA16(af[mi], b1, acc[mi][1]);
      acc[mi][2] = MFMA16(af[mi], b2, acc[mi][2]);
      acc[mi][3] = MFMA16(af[mi], b3, acc[mi][3]);
    }
    __builtin_amdgcn_s_setprio(0);
    if (more) { VMCNT0; BAR; }
  }

#pragma unroll
  for (int mi = 0; mi < 4; ++mi)
#pragma unroll
    for (int nq = 0; nq < 4; ++nq) {
      int e = n0 + wn * 64 + nq * 16 + r;
      size_t rbase = m0 + wm * 64 + mi * 16 + q * 4;
      float bov = bo[e];
#pragma unroll
      for (int j = 0; j < 4; ++j) {
        size_t idx = (rbase + j) * DD + e;
        out[idx] = x[idx] + bov + acc[mi][nq][j];
      }
    }
}

// ---------------- launch ----------------
extern "C" void kernel_launch(void* const* d_in, const int* in_sizes, int n_in,
                              void* d_out, int out_size, void* d_ws, size_t ws_size,
                              hipStream_t stream) {
  const float* x     = (const float*)d_in[0];
  const float* gamma = (const float*)d_in[1];
  const float* beta  = (const float*)d_in[2];
  const float* Wg    = (const float*)d_in[3];
  const float* bg    = (const float*)d_in[4];
  const float* Wv    = (const float*)d_in[5];
  const float* bv    = (const float*)d_in[6];
  const float* Wo    = (const float*)d_in[7];
  const float* bo    = (const float*)d_in[8];
  const float* ldcy  = (const float*)d_in[9];
  float* out = (float*)d_out;

  char* ws = (char*)d_ws;
  // layout: normed bf16 (64MiB) | u/c bf16 (64MiB) | Wg,Wv,Wo bf16 (3x2MiB) | sums f32 (1MiB)
  unsigned short* normed = (unsigned short*)ws;
  unsigned short* u      = (unsigned short*)(ws + (size_t)67108864);
  unsigned short* wgb    = (unsigned short*)(ws + (size_t)134217728);
  unsigned short* wvb    = wgb + 1048576;
  unsigned short* wob    = wvb + 1048576;
  float* sums            = (float*)(ws + (size_t)134217728 + (size_t)3 * 2097152);

  cast_weights<<<3072, 256, 0, stream>>>(Wg, Wv, Wo, wgb, wvb, wob);
  ln_kernel<<<MM, 256, 0, stream>>>(x, gamma, beta, normed);
  gemm_gv<<<dim3(MM / 256 * (DD / 128)), 1024, 0, stream>>>(normed, wgb, wvb, bg, bv, u, sums);
  scan_chunks<<<BB * (DD / 256), 256, 0, stream>>>(sums);
  scan_final<<<BB * NCHUNK * 2, 128, 0, stream>>>(u, sums, ldcy);
  gemm_out<<<dim3(MM / 256 * (DD / 256)), 1024, 0, stream>>>(u, wob, bo, x, out);
}

// Round 9
// 335.534 us; speedup vs baseline: 1.6359x; 1.0590x over previous
//
#include <hip/hip_runtime.h>
#include <cstdint>
#include <cstddef>

// ---------------- problem constants ----------------
#define DD 1024          // feature dim (= K = N per GEMM)
#define TT 8192          // sequence length
#define BB 4             // batch
#define MM (BB*TT)       // 32768 rows
#define NCHUNK 64        // scan chunks over T
#define CLEN 128         // chunk length (NCHUNK*CLEN == TT)
#define EPS 1e-5f
#define NIT 8            // iterations of 2 K-tiles (BK=64) = DD/128

typedef __attribute__((ext_vector_type(8))) short bf16x8;
typedef __attribute__((ext_vector_type(4))) float f32x4;

// ---------------- bf16 helpers (bit-level, RNE) ----------------
__device__ __forceinline__ float bf2f(unsigned short b) {
  union { unsigned int u; float f; } c; c.u = ((unsigned int)b) << 16; return c.f;
}
__device__ __forceinline__ unsigned short f2bf(float f) {
  union { float f; unsigned int u; } c; c.f = f;
  unsigned int lsb = (c.u >> 16) & 1u;
  c.u += 0x7fffu + lsb;
  return (unsigned short)(c.u >> 16);
}

// ---------------- async global->LDS (16B per lane) ----------------
__device__ __forceinline__ void gload16(const void* gsrc, void* ldst) {
  __builtin_amdgcn_global_load_lds(
      (const __attribute__((address_space(1))) unsigned int*)gsrc,
      (__attribute__((address_space(3))) unsigned int*)ldst, 16, 0, 0);
}

#define MFMA16(a, b, c) __builtin_amdgcn_mfma_f32_16x16x32_bf16((a), (b), (c), 0, 0, 0)
#define BAR    __builtin_amdgcn_s_barrier()
#define PRIO1  __builtin_amdgcn_s_setprio(1)
#define PRIO0  __builtin_amdgcn_s_setprio(0)
#define VMW(N) asm volatile("s_waitcnt vmcnt(" #N ")" ::: "memory")

// 64-col rows (128B) = 8 slots of 16B; phys_slot = log_slot ^ (row&7).
// Frag read (16 rows, fixed log slot) spreads over all 8 bank groups -> free.
__device__ __forceinline__ bf16x8 FR(const unsigned short* base, int row, int s8) {
  return *(const bf16x8*)&base[row * 64 + ((s8 ^ (row & 7)) << 3)];
}

// ---------------- kernel 1: cast weights to bf16 ----------------
__global__ __launch_bounds__(256) void cast_weights(
    const float* __restrict__ wg, const float* __restrict__ wv,
    const float* __restrict__ wo,
    unsigned short* __restrict__ owg, unsigned short* __restrict__ owv,
    unsigned short* __restrict__ owo) {
  int i = blockIdx.x * 256 + threadIdx.x;   // over float4 units; 3*262144 total
  const float* src; unsigned short* dst; int off;
  if (i < 262144)       { src = wg; dst = owg; off = i; }
  else if (i < 524288)  { src = wv; dst = owv; off = i - 262144; }
  else                  { src = wo; dst = owo; off = i - 524288; }
  float4 v = ((const float4*)src)[off];
  ushort4 o;
  o.x = f2bf(v.x); o.y = f2bf(v.y); o.z = f2bf(v.z); o.w = f2bf(v.w);
  ((ushort4*)dst)[off] = o;
}

// ---------------- kernel 2: LayerNorm -> bf16 ----------------
__global__ __launch_bounds__(256) void ln_kernel(
    const float* __restrict__ x, const float* __restrict__ gamma,
    const float* __restrict__ beta, unsigned short* __restrict__ normed) {
  size_t row = blockIdx.x;
  int tid = threadIdx.x, lane = tid & 63, wid = tid >> 6;
  float4 v = ((const float4*)(x + row * DD))[tid];
  float s = v.x + v.y + v.z + v.w;
  float q = v.x * v.x + v.y * v.y + v.z * v.z + v.w * v.w;
#pragma unroll
  for (int off = 32; off; off >>= 1) {
    s += __shfl_down(s, off);
    q += __shfl_down(q, off);
  }
  __shared__ float rs[4], rq[4];
  if (lane == 0) { rs[wid] = s; rq[wid] = q; }
  __syncthreads();
  float ts = rs[0] + rs[1] + rs[2] + rs[3];
  float tq = rq[0] + rq[1] + rq[2] + rq[3];
  float mu  = ts * (1.0f / DD);
  float var = tq * (1.0f / DD) - mu * mu;
  float rstd = rsqrtf(var + EPS);
  float4 gm = ((const float4*)gamma)[tid];
  float4 bt = ((const float4*)beta)[tid];
  ushort4 o;
  o.x = f2bf((v.x - mu) * rstd * gm.x + bt.x);
  o.y = f2bf((v.y - mu) * rstd * gm.y + bt.y);
  o.z = f2bf((v.z - mu) * rstd * gm.z + bt.z);
  o.w = f2bf((v.w - mu) * rstd * gm.w + bt.w);
  ((ushort4*)normed)[row * (DD / 4) + tid] = o;
}

// ---------------- kernel 3: fused gate/value GEMM -> u (+ chunk sums) ------
// 256x128 tile, BK=64, 8 waves (2M x 4N), wave owns 128x32 of BOTH outputs.
// m201-style 8-phase/iter (2 K-tiles), 1 half-tile stage per phase,
// vmcnt(6) at phases 4/8 only. LDS 128 KiB, 8-slot swizzle.
__global__ __launch_bounds__(512, 2) void gemm_gv(
    const unsigned short* __restrict__ normed,
    const unsigned short* __restrict__ wg, const unsigned short* __restrict__ wv,
    const float* __restrict__ bg, const float* __restrict__ bv,
    unsigned short* __restrict__ u, float* __restrict__ sums) {
  __shared__ unsigned short As[2][2][128 * 64];   // [dbuf][Mhalf] 64 KiB
  __shared__ unsigned short Bgs[2][128 * 64];     // 32 KiB
  __shared__ unsigned short Bvs[2][128 * 64];     // 32 KiB
  int tid = threadIdx.x, lane = tid & 63, wid = tid >> 6;
  int wm = wid >> 2, wn = wid & 3;         // 2 M-groups x 4 N-groups
  int swz = (blockIdx.x & 7) * (gridDim.x >> 3) + (blockIdx.x >> 3);
  int bx = swz >> 3, by = swz & 7;         // XCD owns contiguous bx chunk
  size_t m0 = (size_t)bx * 256;
  int n0 = by * 128;

  // staging: 1024 16B units per 128x64 half-tile; 2 loads/thread
  int ua = tid, ub = tid + 512;
  int ra = ua >> 3, sa = (ua & 7) ^ (ra & 7);
  int rb = ub >> 3, sb = (ub & 7) ^ (rb & 7);
  const unsigned short* gA = normed + m0 * DD;
  const unsigned short* gBg = wg + (size_t)n0 * DD;
  const unsigned short* gBv = wv + (size_t)n0 * DD;
  auto SA = [&](int t, int h) {
    const unsigned short* s = gA + (size_t)h * 128 * DD + t * 64;
    char* d = (char*)&As[t & 1][h][0];
    gload16(s + (size_t)ra * DD + sa * 8, d + ua * 16);
    gload16(s + (size_t)rb * DD + sb * 8, d + ub * 16);
  };
  auto SG = [&](int t) {
    char* d = (char*)&Bgs[t & 1][0];
    gload16(gBg + (size_t)ra * DD + t * 64 + sa * 8, d + ua * 16);
    gload16(gBg + (size_t)rb * DD + t * 64 + sb * 8, d + ub * 16);
  };
  auto SV = [&](int t) {
    char* d = (char*)&Bvs[t & 1][0];
    gload16(gBv + (size_t)ra * DD + t * 64 + sa * 8, d + ua * 16);
    gload16(gBv + (size_t)rb * DD + t * 64 + sb * 8, d + ub * 16);
  };

  f32x4 accg[8][2], accv[8][2];
#pragma unroll
  for (int a = 0; a < 8; ++a)
#pragma unroll
    for (int b = 0; b < 2; ++b) {
      accg[a][b] = (f32x4){0.f, 0.f, 0.f, 0.f};
      accv[a][b] = (f32x4){0.f, 0.f, 0.f, 0.f};
    }

  // prologue: t0 fully + t1 {Bg,Bv,Ah0}; wait t0 (oldest 8 of 14)
  SG(0); SV(0); SA(0, 0); SA(0, 1); SG(1); SV(1); SA(1, 0);
  VMW(6);
  BAR;

  int r = lane & 15, q = lane >> 4;
  bf16x8 am[4][2], bgf[2][2], bvf[2][2];
  for (int T = 0; T < NIT; ++T) {
    bool more = (T < NIT - 1);
    int t1 = 2 * T + 1, t2 = 2 * T + 2, t3 = 2 * T + 3;
    // ---- P1: A(d0) sub0 + Bg(d0); stage Ah1(t1) ----
#pragma unroll
    for (int mi = 0; mi < 4; ++mi)
#pragma unroll
      for (int kk = 0; kk < 2; ++kk)
        am[mi][kk] = FR(As[0][wm], mi * 16 + r, kk * 4 + q);
#pragma unroll
    for (int ni = 0; ni < 2; ++ni)
#pragma unroll
      for (int kk = 0; kk < 2; ++kk)
        bgf[ni][kk] = FR(Bgs[0], wn * 32 + ni * 16 + r, kk * 4 + q);
    SA(t1, 1);
    BAR; PRIO1;
#pragma unroll
    for (int mi = 0; mi < 4; ++mi)
#pragma unroll
      for (int ni = 0; ni < 2; ++ni)
#pragma unroll
        for (int kk = 0; kk < 2; ++kk)
          accg[mi][ni] = MFMA16(am[mi][kk], bgf[ni][kk], accg[mi][ni]);
    PRIO0; BAR;
    // ---- P2: Bv(d0); stage Bg(t2) ----
#pragma unroll
    for (int ni = 0; ni < 2; ++ni)
#pragma unroll
      for (int kk = 0; kk < 2; ++kk)
        bvf[ni][kk] = FR(Bvs[0], wn * 32 + ni * 16 + r, kk * 4 + q);
    if (more) SG(t2);
    BAR; PRIO1;
#pragma unroll
    for (int mi = 0; mi < 4; ++mi)
#pragma unroll
      for (int ni = 0; ni < 2; ++ni)
#pragma unroll
        for (int kk = 0; kk < 2; ++kk)
          accv[mi][ni] = MFMA16(am[mi][kk], bvf[ni][kk], accv[mi][ni]);
    PRIO0; BAR;
    // ---- P3: A(d0) sub1; stage Bv(t2) ----
#pragma unroll
    for (int mi = 0; mi < 4; ++mi)
#pragma unroll
      for (int kk = 0; kk < 2; ++kk)
        am[mi][kk] = FR(As[0][wm], 64 + mi * 16 + r, kk * 4 + q);
    if (more) SV(t2);
    BAR; PRIO1;
#pragma unroll
    for (int mi = 0; mi < 4; ++mi)
#pragma unroll
      for (int ni = 0; ni < 2; ++ni)
#pragma unroll
        for (int kk = 0; kk < 2; ++kk)
          accv[4 + mi][ni] = MFMA16(am[mi][kk], bvf[ni][kk], accv[4 + mi][ni]);
    PRIO0; BAR;
    // ---- P4: stage Ah0(t2); vmcnt -> t1 fully landed ----
    if (more) { SA(t2, 0); VMW(6); } else { VMW(0); }
    BAR; PRIO1;
#pragma unroll
    for (int mi = 0; mi < 4; ++mi)
#pragma unroll
      for (int ni = 0; ni < 2; ++ni)
#pragma unroll
        for (int kk = 0; kk < 2; ++kk)
          accg[4 + mi][ni] = MFMA16(am[mi][kk], bgf[ni][kk], accg[4 + mi][ni]);
    PRIO0; BAR;
    // ---- P5: A(d1) sub0 + Bg(d1); stage Ah1(t2) ----
#pragma unroll
    for (int mi = 0; mi < 4; ++mi)
#pragma unroll
      for (int kk = 0; kk < 2; ++kk)
        am[mi][kk] = FR(As[1][wm], mi * 16 + r, kk * 4 + q);
#pragma unroll
    for (int ni = 0; ni < 2; ++ni)
#pragma unroll
      for (int kk = 0; kk < 2; ++kk)
        bgf[ni][kk] = FR(Bgs[1], wn * 32 + ni * 16 + r, kk * 4 + q);
    if (more) SA(t2, 1);
    BAR; PRIO1;
#pragma unroll
    for (int mi = 0; mi < 4; ++mi)
#pragma unroll
      for (int ni = 0; ni < 2; ++ni)
#pragma unroll
        for (int kk = 0; kk < 2; ++kk)
          accg[mi][ni] = MFMA16(am[mi][kk], bgf[ni][kk], accg[mi][ni]);
    PRIO0; BAR;
    // ---- P6: Bv(d1); stage Bg(t3) ----
#pragma unroll
    for (int ni = 0; ni < 2; ++ni)
#pragma unroll
      for (int kk = 0; kk < 2; ++kk)
        bvf[ni][kk] = FR(Bvs[1], wn * 32 + ni * 16 + r, kk * 4 + q);
    if (more) SG(t3);
    BAR; PRIO1;
#pragma unroll
    for (int mi = 0; mi < 4; ++mi)
#pragma unroll
      for (int ni = 0; ni < 2; ++ni)
#pragma unroll
        for (int kk = 0; kk < 2; ++kk)
          accv[mi][ni] = MFMA16(am[mi][kk], bvf[ni][kk], accv[mi][ni]);
    PRIO0; BAR;
    // ---- P7: A(d1) sub1; stage Bv(t3) ----
#pragma unroll
    for (int mi = 0; mi < 4; ++mi)
#pragma unroll
      for (int kk = 0; kk < 2; ++kk)
        am[mi][kk] = FR(As[1][wm], 64 + mi * 16 + r, kk * 4 + q);
    if (more) SV(t3);
    BAR; PRIO1;
#pragma unroll
    for (int mi = 0; mi < 4; ++mi)
#pragma unroll
      for (int ni = 0; ni < 2; ++ni)
#pragma unroll
        for (int kk = 0; kk < 2; ++kk)
          accv[4 + mi][ni] = MFMA16(am[mi][kk], bvf[ni][kk], accv[4 + mi][ni]);
    PRIO0; BAR;
    // ---- P8: stage Ah0(t3); vmcnt -> t2 fully landed ----
    if (more) { SA(t3, 0); VMW(6); } else { VMW(0); }
    BAR; PRIO1;
#pragma unroll
    for (int mi = 0; mi < 4; ++mi)
#pragma unroll
      for (int ni = 0; ni < 2; ++ni)
#pragma unroll
        for (int kk = 0; kk < 2; ++kk)
          accg[4 + mi][ni] = MFMA16(am[mi][kk], bgf[ni][kk], accg[4 + mi][ni]);
    PRIO0; BAR;
  }

  // epilogue: u = (2*sigmoid(g)-1)*v + per-chunk colsums (wave-exclusive).
  // C/D layout col=lane&15, row=(lane>>4)*4+j  [m89/m91 verified]
  float psum[2] = {0.f, 0.f};
#pragma unroll
  for (int mi = 0; mi < 8; ++mi)
#pragma unroll
    for (int ni = 0; ni < 2; ++ni) {
      int e = n0 + wn * 32 + ni * 16 + r;
      size_t rbase = m0 + wm * 128 + mi * 16 + q * 4;
      float bgv = bg[e], bvv = bv[e];
#pragma unroll
      for (int j = 0; j < 4; ++j) {
        float gp = accg[mi][ni][j] + bgv;
        float vp = accv[mi][ni][j] + bvv;
        float sg = 1.0f / (1.0f + __expf(-gp));
        float uu = (2.0f * sg - 1.0f) * vp;
        psum[ni] += uu;
        u[(rbase + j) * DD + e] = f2bf(uu);
      }
    }
#pragma unroll
  for (int ni = 0; ni < 2; ++ni) {
    psum[ni] += __shfl_xor(psum[ni], 16);
    psum[ni] += __shfl_xor(psum[ni], 32);
  }
  if (lane < 16) {
    int b = (int)(m0 >> 13);
    int ch = (int)((m0 & 8191) >> 7) + wm;   // wave's 128 rows = one chunk
    size_t sidx = ((size_t)(b * NCHUNK + ch)) * DD + n0 + wn * 32 + lane;
    sums[sidx]      = psum[0];
    sums[sidx + 16] = psum[1];
  }
}

// ---------------- kernel 5: exclusive scan over chunk sums (in place) ------
__global__ __launch_bounds__(256) void scan_chunks(float* __restrict__ sums) {
  int b = blockIdx.x >> 2;
  int e = (blockIdx.x & 3) * 256 + threadIdx.x;
  float vals[NCHUNK];
#pragma unroll
  for (int c = 0; c < NCHUNK; ++c)
    vals[c] = sums[((size_t)(b * NCHUNK + c)) * DD + e];
  float carry = 0.f;
#pragma unroll
  for (int c = 0; c < NCHUNK; ++c) {
    float t = vals[c]; vals[c] = carry; carry += t;
  }
#pragma unroll
  for (int c = 0; c < NCHUNK; ++c)
    sums[((size_t)(b * NCHUNK + c)) * DD + e] = vals[c];
}

// ---------------- kernel 6: chunk-local scan + decay, in place ----------------
__global__ __launch_bounds__(128) void scan_final(
    unsigned short* __restrict__ u, const float* __restrict__ sums,
    const float* __restrict__ log_decay) {
  int bid = blockIdx.x;
  int half = bid & 1, chunk = (bid >> 1) & 63, b = bid >> 7;
  int e0 = half * 512 + threadIdx.x * 4;
  float alpha = log1pf(__expf(log_decay[0]));   // softplus
  float dec  = __expf(-alpha * (float)(chunk * CLEN));
  float step = __expf(-alpha);
  float4 c = *(const float4*)(sums + ((size_t)(b * NCHUNK + chunk)) * DD + e0);
  size_t base = ((size_t)b * TT + (size_t)chunk * CLEN) * DD + e0;
#pragma unroll 4
  for (int i = 0; i < CLEN; ++i) {
    ushort4 w = *(const ushort4*)(u + base + (size_t)i * DD);
    c.x += bf2f(w.x); c.y += bf2f(w.y); c.z += bf2f(w.z); c.w += bf2f(w.w);
    ushort4 o;
    o.x = f2bf(c.x * dec); o.y = f2bf(c.y * dec);
    o.z = f2bf(c.z * dec); o.w = f2bf(c.w * dec);
    *(ushort4*)(u + base + (size_t)i * DD) = o;
    dec *= step;
  }
}

// ---------------- kernel 7: output GEMM + residual ----------------
// 256x256 tile, BK=64, 8 waves (2M x 4N), wave owns 128x64.
// Same 8-phase schedule; vmcnt(4) at phases 4/8. out = x + bo + c@Wo^T
__global__ __launch_bounds__(512, 2) void gemm_out(
    const unsigned short* __restrict__ cmat, const unsigned short* __restrict__ wo,
    const float* __restrict__ bo, const float* __restrict__ x,
    float* __restrict__ out) {
  __shared__ unsigned short As[2][2][128 * 64];   // 64 KiB
  __shared__ unsigned short Bs[2][2][128 * 64];   // 64 KiB
  int tid = threadIdx.x, lane = tid & 63, wid = tid >> 6;
  int wm = wid >> 2, wn = wid & 3;
  int swz = (blockIdx.x & 7) * (gridDim.x >> 3) + (blockIdx.x >> 3);
  int bx = swz >> 2, by = swz & 3;
  size_t m0 = (size_t)bx * 256;
  int n0 = by * 256;
  int bh = wn >> 1, nb = wn & 1;   // wave's B half and quarter-within-half

  int ua = tid, ub = tid + 512;
  int ra = ua >> 3, sa = (ua & 7) ^ (ra & 7);
  int rb = ub >> 3, sb = (ub & 7) ^ (rb & 7);
  const unsigned short* gA = cmat + m0 * DD;
  const unsigned short* gB = wo + (size_t)n0 * DD;
  auto SA = [&](int t, int h) {
    const unsigned short* s = gA + (size_t)h * 128 * DD + t * 64;
    char* d = (char*)&As[t & 1][h][0];
    gload16(s + (size_t)ra * DD + sa * 8, d + ua * 16);
    gload16(s + (size_t)rb * DD + sb * 8, d + ub * 16);
  };
  auto SB = [&](int t, int h) {
    const unsigned short* s = gB + (size_t)h * 128 * DD + t * 64;
    char* d = (char*)&Bs[t & 1][h][0];
    gload16(s + (size_t)ra * DD + sa * 8, d + ua * 16);
    gload16(s + (size_t)rb * DD + sb * 8, d + ub * 16);
  };

  f32x4 acc[8][4];
#pragma unroll
  for (int a = 0; a < 8; ++a)
#pragma unroll
    for (int b = 0; b < 4; ++b) acc[a][b] = (f32x4){0.f, 0.f, 0.f, 0.f};

  // prologue: t0 fully + t1 B halves; wait t0 (oldest 8 of 12)
  SB(0, 0); SB(0, 1); SA(0, 0); SA(0, 1); SB(1, 0); SB(1, 1);
  VMW(4);
  BAR;

  int r = lane & 15, q = lane >> 4;
  bf16x8 am[4][2], b01[2][2], b23[2][2];
  for (int T = 0; T < NIT; ++T) {
    bool more = (T < NIT - 1);
    int t1 = 2 * T + 1, t2 = 2 * T + 2, t3 = 2 * T + 3;
    // ---- P1: A(d0) sub0 + B(d0) n01; stage Ah0(t1) ----
#pragma unroll
    for (int mi = 0; mi < 4; ++mi)
#pragma unroll
      for (int kk = 0; kk < 2; ++kk)
        am[mi][kk] = FR(As[0][wm], mi * 16 + r, kk * 4 + q);
#pragma unroll
    for (int ni = 0; ni < 2; ++ni)
#pragma unroll
      for (int kk = 0; kk < 2; ++kk)
        b01[ni][kk] = FR(Bs[0][bh], nb * 64 + ni * 16 + r, kk * 4 + q);
    SA(t1, 0);
    BAR; PRIO1;
#pragma unroll
    for (int mi = 0; mi < 4; ++mi)
#pragma unroll
      for (int ni = 0; ni < 2; ++ni)
#pragma unroll
        for (int kk = 0; kk < 2; ++kk)
          acc[mi][ni] = MFMA16(am[mi][kk], b01[ni][kk], acc[mi][ni]);
    PRIO0; BAR;
    // ---- P2: B(d0) n23; stage Ah1(t1) ----
#pragma unroll
    for (int ni = 0; ni < 2; ++ni)
#pragma unroll
      for (int kk = 0; kk < 2; ++kk)
        b23[ni][kk] = FR(Bs[0][bh], nb * 64 + 32 + ni * 16 + r, kk * 4 + q);
    SA(t1, 1);
    BAR; PRIO1;
#pragma unroll
    for (int mi = 0; mi < 4; ++mi)
#pragma unroll
      for (int ni = 0; ni < 2; ++ni)
#pragma unroll
        for (int kk = 0; kk < 2; ++kk)
          acc[mi][2 + ni] = MFMA16(am[mi][kk], b23[ni][kk], acc[mi][2 + ni]);
    PRIO0; BAR;
    // ---- P3: A(d0) sub1; stage Bh0(t2) ----
#pragma unroll
    for (int mi = 0; mi < 4; ++mi)
#pragma unroll
      for (int kk = 0; kk < 2; ++kk)
        am[mi][kk] = FR(As[0][wm], 64 + mi * 16 + r, kk * 4 + q);
    if (more) SB(t2, 0);
    BAR; PRIO1;
#pragma unroll
    for (int mi = 0; mi < 4; ++mi)
#pragma unroll
      for (int ni = 0; ni < 2; ++ni)
#pragma unroll
        for (int kk = 0; kk < 2; ++kk)
          acc[4 + mi][2 + ni] = MFMA16(am[mi][kk], b23[ni][kk], acc[4 + mi][2 + ni]);
    PRIO0; BAR;
    // ---- P4: stage Bh1(t2); vmcnt -> t1 fully landed ----
    if (more) { SB(t2, 1); VMW(4); } else { VMW(0); }
    BAR; PRIO1;
#pragma unroll
    for (int mi = 0; mi < 4; ++mi)
#pragma unroll
      for (int ni = 0; ni < 2; ++ni)
#pragma unroll
        for (int kk = 0; kk < 2; ++kk)
          acc[4 + mi][ni] = MFMA16(am[mi][kk], b01[ni][kk], acc[4 + mi][ni]);
    PRIO0; BAR;
    // ---- P5: A(d1) sub0 + B(d1) n01; stage Ah0(t2) ----
#pragma unroll
    for (int mi = 0; mi < 4; ++mi)
#pragma unroll
      for (int kk = 0; kk < 2; ++kk)
        am[mi][kk] = FR(As[1][wm], mi * 16 + r, kk * 4 + q);
#pragma unroll
    for (int ni = 0; ni < 2; ++ni)
#pragma unroll
      for (int kk = 0; kk < 2; ++kk)
        b01[ni][kk] = FR(Bs[1][bh], nb * 64 + ni * 16 + r, kk * 4 + q);
    if (more) SA(t2, 0);
    BAR; PRIO1;
#pragma unroll
    for (int mi = 0; mi < 4; ++mi)
#pragma unroll
      for (int ni = 0; ni < 2; ++ni)
#pragma unroll
        for (int kk = 0; kk < 2; ++kk)
          acc[mi][ni] = MFMA16(am[mi][kk], b01[ni][kk], acc[mi][ni]);
    PRIO0; BAR;
    // ---- P6: B(d1) n23; stage Ah1(t2) ----
#pragma unroll
    for (int ni = 0; ni < 2; ++ni)
#pragma unroll
      for (int kk = 0; kk < 2; ++kk)
        b23[ni][kk] = FR(Bs[1][bh], nb * 64 + 32 + ni * 16 + r, kk * 4 + q);
    if (more) SA(t2, 1);
    BAR; PRIO1;
#pragma unroll
    for (int mi = 0; mi < 4; ++mi)
#pragma unroll
      for (int ni = 0; ni < 2; ++ni)
#pragma unroll
        for (int kk = 0; kk < 2; ++kk)
          acc[mi][2 + ni] = MFMA16(am[mi][kk], b23[ni][kk], acc[mi][2 + ni]);
    PRIO0; BAR;
    // ---- P7: A(d1) sub1; stage Bh0(t3) ----
#pragma unroll
    for (int mi = 0; mi < 4; ++mi)
#pragma unroll
      for (int kk = 0; kk < 2; ++kk)
        am[mi][kk] = FR(As[1][wm], 64 + mi * 16 + r, kk * 4 + q);
    if (more) SB(t3, 0);
    BAR; PRIO1;
#pragma unroll
    for (int mi = 0; mi < 4; ++mi)
#pragma unroll
      for (int ni = 0; ni < 2; ++ni)
#pragma unroll
        for (int kk = 0; kk < 2; ++kk)
          acc[4 + mi][2 + ni] = MFMA16(am[mi][kk], b23[ni][kk], acc[4 + mi][2 + ni]);
    PRIO0; BAR;
    // ---- P8: stage Bh1(t3); vmcnt -> t2 fully landed ----
    if (more) { SB(t3, 1); VMW(4); } else { VMW(0); }
    BAR; PRIO1;
#pragma unroll
    for (int mi = 0; mi < 4; ++mi)
#pragma unroll
      for (int ni = 0; ni < 2; ++ni)
#pragma unroll
        for (int kk = 0; kk < 2; ++kk)
          acc[4 + mi][ni] = MFMA16(am[mi][kk], b01[ni][kk], acc[4 + mi][ni]);
    PRIO0; BAR;
  }

#pragma unroll
  for (int mi = 0; mi < 8; ++mi)
#pragma unroll
    for (int nq = 0; nq < 4; ++nq) {
      int e = n0 + wn * 64 + nq * 16 + r;
      size_t rbase = m0 + wm * 128 + mi * 16 + q * 4;
      float bov = bo[e];
#pragma unroll
      for (int j = 0; j < 4; ++j) {
        size_t idx = (rbase + j) * DD + e;
        out[idx] = x[idx] + bov + acc[mi][nq][j];
      }
    }
}

// ---------------- launch ----------------
extern "C" void kernel_launch(void* const* d_in, const int* in_sizes, int n_in,
                              void* d_out, int out_size, void* d_ws, size_t ws_size,
                              hipStream_t stream) {
  const float* x     = (const float*)d_in[0];
  const float* gamma = (const float*)d_in[1];
  const float* beta  = (const float*)d_in[2];
  const float* Wg    = (const float*)d_in[3];
  const float* bg    = (const float*)d_in[4];
  const float* Wv    = (const float*)d_in[5];
  const float* bv    = (const float*)d_in[6];
  const float* Wo    = (const float*)d_in[7];
  const float* bo    = (const float*)d_in[8];
  const float* ldcy  = (const float*)d_in[9];
  float* out = (float*)d_out;

  char* ws = (char*)d_ws;
  // layout: normed bf16 (64MiB) | u/c bf16 (64MiB) | Wg,Wv,Wo bf16 (3x2MiB) | sums f32 (1MiB)
  unsigned short* normed = (unsigned short*)ws;
  unsigned short* u      = (unsigned short*)(ws + (size_t)67108864);
  unsigned short* wgb    = (unsigned short*)(ws + (size_t)134217728);
  unsigned short* wvb    = wgb + 1048576;
  unsigned short* wob    = wvb + 1048576;
  float* sums            = (float*)(ws + (size_t)134217728 + (size_t)3 * 2097152);

  cast_weights<<<3072, 256, 0, stream>>>(Wg, Wv, Wo, wgb, wvb, wob);
  ln_kernel<<<MM, 256, 0, stream>>>(x, gamma, beta, normed);
  gemm_gv<<<dim3(MM / 256 * (DD / 128)), 512, 0, stream>>>(normed, wgb, wvb, bg, bv, u, sums);
  scan_chunks<<<BB * (DD / 256), 256, 0, stream>>>(sums);
  scan_final<<<BB * NCHUNK * 2, 128, 0, stream>>>(u, sums, ldcy);
  gemm_out<<<dim3(MM / 256 * (DD / 256)), 512, 0, stream>>>(u, wob, bo, x, out);
}